// Round 9
// baseline (24.458 us; speedup 1.0000x reference)
//
#include <hip/hip_runtime.h>
#include <math.h>

#define GRIDN 128
#define NSAMP 192
#define BLOCK 256

__global__ __launch_bounds__(BLOCK) void plenoxel_render_kernel(
    const float* __restrict__ vox_grid,   // [128][128][128][28]
    const float* __restrict__ origins,    // [R][3]
    const float* __restrict__ dirs_in,    // [R][3]
    float* __restrict__ out)              // [R][3]
{
    __shared__ uint2  ow_s[NSAMP][9];     // 13824 B; stride 9 (72B) spreads banks
    __shared__ float4 scs_s[NSAMP];       //  3072 B {sigma, r, g, b}
    __shared__ float  sh_s[9];
    __shared__ int    lastw[4];
    __shared__ float  wtot[3];
    __shared__ float  redr[3], redg[3], redb[3];

    const int ray  = blockIdx.x;
    const int tid  = threadIdx.x;
    const int lane = tid & 63;
    const int wave = tid >> 6;              // 0..3

    // ---- per-ray setup (uniform per block) ----
    const float ox = origins[ray * 3 + 0];
    const float oy = origins[ray * 3 + 1];
    const float oz = origins[ray * 3 + 2];
    float dx = dirs_in[ray * 3 + 0];
    float dy = dirs_in[ray * 3 + 1];
    float dz = dirs_in[ray * 3 + 2];
    const float rn = 1.0f / sqrtf(dx * dx + dy * dy + dz * dz);
    dx *= rn; dy *= rn; dz *= rn;

    // SH basis into LDS (unit dir: st*cp=dx, st*sp=dy, ct=dz)
    if (tid == 0) {
        sh_s[0] = 0.28209479177387814f;
        sh_s[1] = 0.4886025119029199f * dy;
        sh_s[2] = 0.4886025119029199f * dz;
        sh_s[3] = 0.4886025119029199f * dx;
        sh_s[4] = 1.0925484305920792f * dx * dy;
        sh_s[5] = 1.0925484305920792f * dy * dz;
        sh_s[6] = 0.31539156525252005f * (3.f * dz * dz - 1.f);
        sh_s[7] = 1.0925484305920792f * dx * dz;
        sh_s[8] = 0.5462742152960396f * (dx * dx - dy * dy);
    }

    // ---- phase 0: per-sample corner offsets + weights (thread = sample) ----
    bool any_valid = false;
    if (tid < NSAMP) {
        scs_s[tid] = make_float4(0.f, 0.f, 0.f, 0.f);   // dead samples contribute 0
        const float t  = (float)tid;
        const float px = fmaf(dx, t, ox);
        const float py = fmaf(dy, t, oy);
        const float pz = fmaf(dz, t, oz);
        const float fx = floorf(px), fy = floorf(py), fz = floorf(pz);
        const int   ix = (int)fx, iy = (int)fy, iz = (int)fz;
        const float rx = px - fx, ry = py - fy, rz = pz - fz;
        #pragma unroll
        for (int g = 0; g < 8; ++g) {
            const int cx = (g >> 2) & 1, cy = (g >> 1) & 1, cz = g & 1;
            const int X = ix + cx, Y = iy + cy, Z = iz + cz;
            const bool valid = ((unsigned)X < GRIDN) & ((unsigned)Y < GRIDN) & ((unsigned)Z < GRIDN);
            any_valid |= valid;
            const int Xc = min(max(X, 0), GRIDN - 1);
            const int Yc = min(max(Y, 0), GRIDN - 1);
            const int Zc = min(max(Z, 0), GRIDN - 1);
            const unsigned off = (unsigned)((((Xc << 7) + Yc) << 7) + Zc) * 112u;
            const float w = (cx ? rx : 1.f - rx) * (cy ? ry : 1.f - ry) * (cz ? rz : 1.f - rz);
            ow_s[tid][g] = make_uint2(off, __float_as_uint(valid ? w : 0.f));
        }
    }
    {
        const unsigned long long m = __ballot(any_valid);
        if (lane == 0) lastw[wave] = m ? (wave * 64 + 63 - __clzll(m)) : -1;
    }
    __syncthreads();
    const int last_live = max(max(lastw[0], lastw[1]), max(lastw[2], lastw[3]));

    // ---- per-lane color multipliers (loop-invariant) ----
    const int q = lane & 7;
    float mr[4], mg[4], mb[4];
    #pragma unroll
    for (int j = 0; j < 4; ++j) {
        const int c = q * 4 + j;
        mr[j] = (c >= 1  && c <= 9 ) ? sh_s[c - 1]  : 0.f;
        mg[j] = (c >= 10 && c <= 18) ? sh_s[c - 10] : 0.f;
        mb[j] = (c >= 19 && c <= 27) ? sh_s[c - 19] : 0.f;
    }

    // ---- phase 1: gather, 2 samples per lane => 16 loads in flight ----
    // lane = s_sub(3b)*8 + q(3b); wave covers 16 samples/pass (sA and sB=sA+8),
    // block covers 64 samples/pass, 3 passes total.
    {
        const int s_sub = lane >> 3;          // 0..7
        const int qe    = (q == 7) ? 6 : q;   // dup quad 6, weight forced 0
        const char* base = (const char*)vox_grid;

        #pragma unroll
        for (int p = 0; p < NSAMP / 64; ++p) {     // 3 passes
            const int sbase = p * 64 + wave * 16;
            if (sbase > last_live) break;          // wave-uniform dead suffix
            const int sA = sbase + s_sub;
            const int sB = sA + 8;
            float4 accA = make_float4(0.f, 0.f, 0.f, 0.f);
            float4 accB = make_float4(0.f, 0.f, 0.f, 0.f);
            #pragma unroll
            for (int g = 0; g < 8; ++g) {
                const uint2 owA = ow_s[sA][g];
                const uint2 owB = ow_s[sB][g];
                const float4 vA = *(const float4*)(base + owA.x + qe * 16);
                const float4 vB = *(const float4*)(base + owB.x + qe * 16);
                const float wA = (q == 7) ? 0.f : __uint_as_float(owA.y);
                const float wB = (q == 7) ? 0.f : __uint_as_float(owB.y);
                accA.x = fmaf(wA, vA.x, accA.x);
                accA.y = fmaf(wA, vA.y, accA.y);
                accA.z = fmaf(wA, vA.z, accA.z);
                accA.w = fmaf(wA, vA.w, accA.w);
                accB.x = fmaf(wB, vB.x, accB.x);
                accB.y = fmaf(wB, vB.y, accB.y);
                accB.z = fmaf(wB, vB.z, accB.z);
                accB.w = fmaf(wB, vB.w, accB.w);
            }

            float prA = accA.x * mr[0] + accA.y * mr[1] + accA.z * mr[2] + accA.w * mr[3];
            float pgA = accA.x * mg[0] + accA.y * mg[1] + accA.z * mg[2] + accA.w * mg[3];
            float pbA = accA.x * mb[0] + accA.y * mb[1] + accA.z * mb[2] + accA.w * mb[3];
            float prB = accB.x * mr[0] + accB.y * mr[1] + accB.z * mr[2] + accB.w * mr[3];
            float pgB = accB.x * mg[0] + accB.y * mg[1] + accB.z * mg[2] + accB.w * mg[3];
            float pbB = accB.x * mb[0] + accB.y * mb[1] + accB.z * mb[2] + accB.w * mb[3];
            const float psA = fmaxf(accA.x, 0.f);   // full sigma in lane q==0
            const float psB = fmaxf(accB.x, 0.f);

            #pragma unroll
            for (int m = 1; m < 8; m <<= 1) {       // two independent chains
                prA += __shfl_xor(prA, m, 64);
                prB += __shfl_xor(prB, m, 64);
                pgA += __shfl_xor(pgA, m, 64);
                pgB += __shfl_xor(pgB, m, 64);
                pbA += __shfl_xor(pbA, m, 64);
                pbB += __shfl_xor(pbB, m, 64);
            }
            if (q == 0) {
                scs_s[sA] = make_float4(psA,
                                        fminf(fmaxf(prA, 0.f), 1.f),
                                        fminf(fmaxf(pgA, 0.f), 1.f),
                                        fminf(fmaxf(pbA, 0.f), 1.f));
                scs_s[sB] = make_float4(psB,
                                        fminf(fmaxf(prB, 0.f), 1.f),
                                        fminf(fmaxf(pgB, 0.f), 1.f),
                                        fminf(fmaxf(pbB, 0.f), 1.f));
            }
        }
    }
    __syncthreads();

    // ---- phase 2: transmittance scan + accumulation (thread = sample) ----
    float sigma = 0.f, incl = 0.f, cr = 0.f, cg = 0.f, cb = 0.f;
    if (tid < NSAMP) {
        const float4 sc = scs_s[tid];
        sigma = sc.x; cr = sc.y; cg = sc.z; cb = sc.w;

        incl = sigma;
        #pragma unroll
        for (int d = 1; d < 64; d <<= 1) {
            const float v = __shfl_up(incl, d, 64);
            if (lane >= d) incl += v;
        }
        if (lane == 63) wtot[wave] = incl;
    }
    __syncthreads();

    if (tid < NSAMP) {
        float off = 0.f;
        for (int wv = 0; wv < wave; ++wv) off += wtot[wv];   // wave-uniform
        const float excl  = off + (incl - sigma);
        const float trans = expf(-excl);
        const float alpha = 1.f - expf(-sigma);
        const float wt    = trans * alpha;

        float r = wt * cr, g2 = wt * cg, b = wt * cb;
        #pragma unroll
        for (int d = 32; d >= 1; d >>= 1) {
            r  += __shfl_xor(r,  d, 64);
            g2 += __shfl_xor(g2, d, 64);
            b  += __shfl_xor(b,  d, 64);
        }
        if (lane == 0) { redr[wave] = r; redg[wave] = g2; redb[wave] = b; }
    }
    __syncthreads();

    if (tid == 0) {
        const float tfinal = expf(-(wtot[0] + wtot[1] + wtot[2]));
        out[ray * 3 + 0] = redr[0] + redr[1] + redr[2] + tfinal;
        out[ray * 3 + 1] = redg[0] + redg[1] + redg[2] + tfinal;
        out[ray * 3 + 2] = redb[0] + redb[1] + redb[2] + tfinal;
    }
}

extern "C" void kernel_launch(void* const* d_in, const int* in_sizes, int n_in,
                              void* d_out, int out_size, void* d_ws, size_t ws_size,
                              hipStream_t stream) {
    const float* vox_grid = (const float*)d_in[0];
    const float* origins  = (const float*)d_in[1];
    const float* dirs     = (const float*)d_in[2];
    float*       out      = (float*)d_out;
    const int R = in_sizes[1] / 3;   // 2048 rays
    plenoxel_render_kernel<<<R, BLOCK, 0, stream>>>(vox_grid, origins, dirs, out);
}